// Round 4
// baseline (117.961 us; speedup 1.0000x reference)
//
#include <hip/hip_runtime.h>
#include <math.h>

#define BB 4
#define HH 256
#define WW 256
#define NN (BB*HH*WW)          // 262144
typedef unsigned long long u64;
typedef unsigned int u32;

// ws layout (byte offsets):
//   0    .. 23   : 6 float accumulators (0=inter 1=sum_p 2=sum_t 3=bce 4=focal 5=bnd)
//   128  .. 1151 : flag1[256] u32  (mask-build done per block)
//   1152 .. 2175 : flag2[256] u32  (accumulation done per block)
//   4096 .. +64K : column-major zero masks, u64 maskT[img][b][c][w]
//                  bit r of word w = "row 64w+r is zero"
#define FLAG1_OFF 128
#define FLAG2_OFF 1152
#define MASK_OFF  4096
#define MAGIC1 0x13579BDFu     // != 0xAAAAAAAA poison
#define MAGIC2 0x2468ACE1u
#define SENT 100000            // no-zero-in-column sentinel (g^2 ~1e10 >> 130050 max real)

// ---------------------------------------------------------------------------
// Single fused kernel. 256 blocks (one per CU, all co-resident) x 256 threads.
//   A: lanes 0..31 build 32 mask words each block (2 MB read spread on 256 CUs)
//   B: elementwise loss terms (independent of masks -> overlaps the barrier)
//   barrier 1 (device-scope flags)
//   C: vertical EDT via register bit-scans
//   D: horizontal min-plus, outward scan with exact early exit
//   E: block reduce + device atomics; barrier 2; block 0 writes the scalar
// ---------------------------------------------------------------------------
__global__ __launch_bounds__(256)
void combo_fused(const float* __restrict__ pred,
                 const float* __restrict__ targ,
                 float* __restrict__ ws,
                 float* __restrict__ out) {
    __shared__ float2 G[4][WW];     // [row-in-band][col] = (g2_pred, g2_targ)
    __shared__ float red[4][6];

    const int blk = blockIdx.x;     // 0..255
    const int tid = threadIdx.x;    // 0..255
    u32* flag1 = (u32*)((char*)ws + FLAG1_OFF);
    u32* flag2 = (u32*)((char*)ws + FLAG2_OFF);
    u64* maskT = (u64*)((char*)ws + MASK_OFF);

    // ---- A: build this block's 32 mask words (lanes 0..31)
    if (tid < 32) {
        int t   = blk * 32 + tid;   // word id 0..8191
        int c   = t & 255;
        int w   = (t >> 8) & 3;
        int b   = (t >> 10) & 3;
        int img = t >> 12;
        // zero predicate: pred_bin = (x > 0.5) -> zero iff x <= 0.5; targ in {0,1} same test
        const float* s = (img ? targ : pred) + b * (HH * WW) + (w * 64) * WW + c;
        u64 m = 0;
        #pragma unroll
        for (int r = 0; r < 64; ++r) {
            float x = s[r * WW];
            m |= ((u64)(x <= 0.5f)) << r;
        }
        maskT[(((img * BB + b) * WW + c) << 2) + w] = m;
    }
    if (blk == 0 && tid < 6) ws[tid] = 0.0f;   // zero accumulators (released via flag1[0])
    __threadfence();                            // device-visible before flag release
    __syncthreads();
    if (tid == 0)
        __hip_atomic_store(&flag1[blk], MAGIC1, __ATOMIC_RELEASE, __HIP_MEMORY_SCOPE_AGENT);

    // ---- B: elementwise terms (no mask dependency -> runs while others build)
    const int b    = blk >> 6;
    const int band = blk & 63;
    const int i0   = band << 2;     // first row of this block's 4-row band
    const int j    = tid;           // this thread's column

    float sPT = 0.0f, sP = 0.0f, sT = 0.0f, sBCE = 0.0f, sFOC = 0.0f, sBND = 0.0f;
    #pragma unroll
    for (int k = 0; k < 4; ++k) {
        int idx = (b * HH + (i0 + k)) * WW + j;
        float x = pred[idx];
        float t = targ[idx];

        float p   = 1.0f / (1.0f + expf(-x));
        float ax  = fabsf(x);
        float l1p = log1pf(expf(-ax));
        float bce_el = fmaxf(x, 0.0f) - x * t + l1p;      // BCEWithLogits
        float lsx  = fminf(x, 0.0f) - l1p;                 // log(p)
        float lsnx = -fmaxf(x, 0.0f) - l1p;                // log(1-p)
        float bce_f = -(t * lsx + (1.0f - t) * lsnx);
        float pt = p * t + (1.0f - p) * (1.0f - t);
        float om = 1.0f - pt;

        sPT  += p * t;
        sP   += p;
        sT   += t;
        sBCE += bce_el;
        sFOC += om * om * bce_f;                           // alpha=1, gamma=2
    }

    // ---- barrier 1: wait until all 256 blocks published their masks
    {
        bool ok;
        do {
            u32 v = __hip_atomic_load(&flag1[tid], __ATOMIC_ACQUIRE, __HIP_MEMORY_SCOPE_AGENT);
            ok = (v == MAGIC1);
        } while (!__syncthreads_and(ok));
    }

    // ---- C: vertical distances for column j, 4 band rows, both images
    const int wq = i0 >> 6;         // word containing the band (uniform)
    const int o0 = i0 & 63;         // bit offset (<=60, so o0+3 <= 63)
    float g2v[2][4];
    #pragma unroll
    for (int img = 0; img < 2; ++img) {
        const u64* mp = maskT + (((img * BB + b) * WW + j) << 2);
        u64 M0 = mp[0], M1 = mp[1], M2 = mp[2], M3 = mp[3];

        int t1 = __ffsll(M1), t2 = __ffsll(M2), t3 = __ffsll(M3);
        int f1 = t1 ? 64 + t1 - 1  : SENT;
        int f2 = t2 ? 128 + t2 - 1 : SENT;
        int f3 = t3 ? 192 + t3 - 1 : SENT;
        int r0 = __ffsll(__brevll(M0));
        int r1 = __ffsll(__brevll(M1));
        int r2 = __ffsll(__brevll(M2));
        int l0 = r0 ? 64 - r0  : -SENT;
        int l1 = r1 ? 128 - r1 : -SENT;
        int l2 = r2 ? 192 - r2 : -SENT;

        int s3 = f3;
        int s2 = min(f2, s3);
        int s1 = min(f1, s2);
        int NF = (wq == 0) ? s1 : (wq == 1) ? s2 : (wq == 2) ? s3 : SENT;
        int q0 = l0;
        int q1 = max(q0, l1);
        int q2 = max(q1, l2);
        int PB = (wq == 0) ? -SENT : (wq == 1) ? q0 : (wq == 2) ? q1 : q2;
        u64 Mq = (wq == 0) ? M0 : (wq == 1) ? M1 : (wq == 2) ? M2 : M3;

        #pragma unroll
        for (int kk = 0; kk < 4; ++kk) {
            int i = i0 + kk, o = o0 + kk;            // o <= 63
            u64 sh  = Mq >> o;
            int tn  = __ffsll(sh);
            int n   = tn ? i + tn - 1 : NF;          // nearest zero row >= i
            u64 shl = Mq << (63 - o);
            int tp  = __ffsll(__brevll(shl));
            int p   = tp ? i - (tp - 1) : PB;        // nearest zero row <= i
            int g   = min(n - i, i - p);
            g2v[img][kk] = (float)g * (float)g;
        }
    }
    #pragma unroll
    for (int kk = 0; kk < 4; ++kk)
        G[kk][j] = make_float2(g2v[0][kk], g2v[1][kk]);
    __syncthreads();

    // ---- D: horizontal min-plus, outward scan with exact early exit
    float d2p[4], d2t[4];
    #pragma unroll
    for (int k = 0; k < 4; ++k) {
        float2 g = G[k][j];
        d2p[k] = g.x; d2t[k] = g.y;
    }
    for (int r = 1; r < WW; ++r) {
        float r2 = (float)(r * r);
        float dmax = fmaxf(fmaxf(fmaxf(d2p[0], d2p[1]), fmaxf(d2p[2], d2p[3])),
                           fmaxf(fmaxf(d2t[0], d2t[1]), fmaxf(d2t[2], d2t[3])));
        if (__all(r2 >= dmax)) break;
        int lo = j - r, hi = j + r;
        if (lo >= 0) {
            #pragma unroll
            for (int k = 0; k < 4; ++k) {
                float2 g = G[k][lo];
                d2p[k] = fminf(d2p[k], g.x + r2);
                d2t[k] = fminf(d2t[k], g.y + r2);
            }
        }
        if (hi < WW) {
            #pragma unroll
            for (int k = 0; k < 4; ++k) {
                float2 g = G[k][hi];
                d2p[k] = fminf(d2p[k], g.x + r2);
                d2t[k] = fminf(d2t[k], g.y + r2);
            }
        }
    }
    #pragma unroll
    for (int k = 0; k < 4; ++k)
        sBND += fabsf(sqrtf(d2p[k]) - sqrtf(d2t[k]));

    // ---- E: block reduction + device atomics
    float vals[6] = { sPT, sP, sT, sBCE, sFOC, sBND };
    int lane = tid & 63;
    int wave = tid >> 6;
    #pragma unroll
    for (int k = 0; k < 6; ++k) {
        float v = vals[k];
        #pragma unroll
        for (int off = 32; off > 0; off >>= 1)
            v += __shfl_down(v, off, 64);
        if (lane == 0) red[wave][k] = v;
    }
    __syncthreads();
    if (tid < 6) {
        float s = red[0][tid] + red[1][tid] + red[2][tid] + red[3][tid];
        atomicAdd(&ws[tid], s);                    // device-scope by default
    }
    __threadfence();
    __syncthreads();
    if (tid == 0)
        __hip_atomic_store(&flag2[blk], MAGIC2, __ATOMIC_RELEASE, __HIP_MEMORY_SCOPE_AGENT);

    // ---- F: block 0 finalizes after all blocks accumulated
    if (blk == 0) {
        bool ok;
        do {
            u32 v = __hip_atomic_load(&flag2[tid], __ATOMIC_ACQUIRE, __HIP_MEMORY_SCOPE_AGENT);
            ok = (v == MAGIC2);
        } while (!__syncthreads_and(ok));
        if (tid == 0) {
            float inter = atomicAdd(&ws[0], 0.0f);
            float sp    = atomicAdd(&ws[1], 0.0f);
            float st    = atomicAdd(&ws[2], 0.0f);
            float bce   = atomicAdd(&ws[3], 0.0f);
            float foc   = atomicAdd(&ws[4], 0.0f);
            float bnd   = atomicAdd(&ws[5], 0.0f);
            float invN = 1.0f / (float)NN;
            float dice = 1.0f - (2.0f * inter + 1.0f) / (sp + st + 1.0f);
            out[0] = 0.5f * dice + 0.5f * (bce * invN)
                   + 0.1f * (bnd * invN) + 0.2f * (foc * invN);
        }
    }
}

extern "C" void kernel_launch(void* const* d_in, const int* in_sizes, int n_in,
                              void* d_out, int out_size, void* d_ws, size_t ws_size,
                              hipStream_t stream) {
    const float* pred = (const float*)d_in[0];
    const float* targ = (const float*)d_in[1];
    combo_fused<<<BB * 64, 256, 0, stream>>>(pred, targ, (float*)d_ws, (float*)d_out);
}

// Round 5
// 69.589 us; speedup vs baseline: 1.6951x; 1.6951x over previous
//
#include <hip/hip_runtime.h>
#include <math.h>

#define BB 4
#define HH 256
#define WW 256
#define NN (BB*HH*WW)          // 262144
typedef unsigned long long u64;
typedef unsigned int u32;

// ws layout:
//   float[0..5]  accumulators: 0=intersection 1=sum_p 2=sum_t 3=bce 4=focal 5=boundary
//   float[6]     completion counter (as unsigned)
//   byte 256 ...: column-major zero masks, u64 maskT[img][b][c][w]
//                 2*4*256*4 = 8192 u64 = 64 KB. bit r of word w = row 64w+r is "zero".
#define MASK_OFF_BYTES 256
#define SENT 100000            // no-zero-in-column sentinel (g^2 ~1e10 >> 130050 max real)

// ---------------------------------------------------------------------------
// Kernel A: build column-major zero bitmasks for both thresholded images.
// Each thread builds a 32-bit HALF of a mask word (little-endian u32 halves
// of the u64), so the 16384 half-words spread over 256 blocks x 64 threads
// = every CU, 32 coalesced row-strided loads per thread.
// Also zeroes the 6 accumulators + completion counter.
// ---------------------------------------------------------------------------
__global__ __launch_bounds__(64)
void build_masks(const float* __restrict__ pred,
                 const float* __restrict__ targ,
                 float* __restrict__ ws) {
    int t = blockIdx.x * 64 + threadIdx.x;    // 0..16383
    if (t < 7) ws[t] = 0.0f;

    int c   = t & 255;          // consecutive lanes -> consecutive columns (coalesced)
    int h   = (t >> 8) & 1;     // which 32-bit half of the word
    int w   = (t >> 9) & 3;     // 64-row word index
    int b   = (t >> 11) & 3;
    int img = t >> 13;

    // zero predicate: pred_bin = (x > 0.5) -> zero iff x <= 0.5; targ in {0,1} -> same test
    const float* s = (img ? targ : pred) + b * (HH * WW) + (w * 64 + h * 32) * WW + c;
    u32 m = 0;
    #pragma unroll
    for (int r = 0; r < 32; ++r) {
        float x = s[r * WW];
        m |= ((u32)(x <= 0.5f)) << r;
    }
    u32* mask32 = (u32*)((char*)ws + MASK_OFF_BYTES);
    mask32[(((((img * BB + b) * WW + c) << 2) + w) << 1) + h] = m;
}

// ---------------------------------------------------------------------------
// Kernel B: per-(b, 4-row band) fused kernel.
//   phase 2: vertical EDT via register bit-scans (O(1) per row, no LDS)
//   phase 3: horizontal min-plus, outward scan with exact early exit
//   phase 4: elementwise loss terms + block reduction + atomics
//   phase 5: last-finishing block combines accumulators -> d_out
// ---------------------------------------------------------------------------
__global__ __launch_bounds__(256)
void band_fused(const float* __restrict__ pred,
                const float* __restrict__ targ,
                float* __restrict__ ws,
                float* __restrict__ out) {
    __shared__ float2 G[4][WW];     // [row-in-band][col] = (g2_pred, g2_targ)
    __shared__ float red[4][6];
    __shared__ int amLast;

    int blk  = blockIdx.x;          // 0..255
    int b    = blk >> 6;
    int band = blk & 63;
    int i0   = band << 2;           // first row of band
    int wq   = i0 >> 6;             // word containing the band (uniform)
    int o0   = i0 & 63;             // bit offset (<=60, so o0+3 <= 63)
    int c    = threadIdx.x;         // this thread's column

    const u64* maskT = (const u64*)((const char*)ws + MASK_OFF_BYTES);

    // ---- phase 2: vertical distances for this column, 4 band rows, both images
    float g2v[2][4];
    #pragma unroll
    for (int img = 0; img < 2; ++img) {
        const u64* mp = maskT + (((img * BB + b) * WW + c) << 2);
        u64 M0 = mp[0], M1 = mp[1], M2 = mp[2], M3 = mp[3];

        // per-word first (lowest) set-bit global index, sentinel SENT
        int t1 = __ffsll(M1), t2 = __ffsll(M2), t3 = __ffsll(M3);
        int f1 = t1 ? 64 + t1 - 1  : SENT;
        int f2 = t2 ? 128 + t2 - 1 : SENT;
        int f3 = t3 ? 192 + t3 - 1 : SENT;
        // per-word last (highest) set-bit global index, sentinel -SENT
        int r0 = __ffsll(__brevll(M0));
        int r1 = __ffsll(__brevll(M1));
        int r2 = __ffsll(__brevll(M2));
        int l0 = r0 ? 64 - r0  : -SENT;
        int l1 = r1 ? 128 - r1 : -SENT;
        int l2 = r2 ? 192 - r2 : -SENT;

        // suffix-firsts (words above wq) / prefix-lasts (words below wq)
        int s3 = f3;
        int s2 = min(f2, s3);
        int s1 = min(f1, s2);
        int NF = (wq == 0) ? s1 : (wq == 1) ? s2 : (wq == 2) ? s3 : SENT;
        int q0 = l0;
        int q1 = max(q0, l1);
        int q2 = max(q1, l2);
        int PB = (wq == 0) ? -SENT : (wq == 1) ? q0 : (wq == 2) ? q1 : q2;
        u64 Mq = (wq == 0) ? M0 : (wq == 1) ? M1 : (wq == 2) ? M2 : M3;

        #pragma unroll
        for (int kk = 0; kk < 4; ++kk) {
            int i = i0 + kk, o = o0 + kk;            // o <= 63
            u64 sh  = Mq >> o;                       // bits at/above i within word
            int tn  = __ffsll(sh);
            int n   = tn ? i + tn - 1 : NF;          // nearest zero row >= i
            u64 shl = Mq << (63 - o);                // bits at/below i within word
            int tp  = __ffsll(__brevll(shl));
            int p   = tp ? i - (tp - 1) : PB;        // nearest zero row <= i
            int g   = min(n - i, i - p);
            g2v[img][kk] = (float)g * (float)g;
        }
    }
    #pragma unroll
    for (int kk = 0; kk < 4; ++kk)
        G[kk][c] = make_float2(g2v[0][kk], g2v[1][kk]);
    __syncthreads();

    // ---- phase 3: horizontal min-plus, outward scan from j with exact early exit.
    // Any candidate at radius r has value >= r^2, so once r^2 >= current-best
    // (for every lane of the wave) no improvement is possible.
    int j = threadIdx.x;
    float d2p[4], d2t[4];
    #pragma unroll
    for (int k = 0; k < 4; ++k) {    // r = 0 candidate
        float2 g = G[k][j];
        d2p[k] = g.x; d2t[k] = g.y;
    }
    for (int r = 1; r < WW; ++r) {
        float r2 = (float)(r * r);
        float dmax = fmaxf(fmaxf(fmaxf(d2p[0], d2p[1]), fmaxf(d2p[2], d2p[3])),
                           fmaxf(fmaxf(d2t[0], d2t[1]), fmaxf(d2t[2], d2t[3])));
        if (__all(r2 >= dmax)) break;
        int lo = j - r, hi = j + r;
        if (lo >= 0) {
            #pragma unroll
            for (int k = 0; k < 4; ++k) {
                float2 g = G[k][lo];
                d2p[k] = fminf(d2p[k], g.x + r2);
                d2t[k] = fminf(d2t[k], g.y + r2);
            }
        }
        if (hi < WW) {
            #pragma unroll
            for (int k = 0; k < 4; ++k) {
                float2 g = G[k][hi];
                d2p[k] = fminf(d2p[k], g.x + r2);
                d2t[k] = fminf(d2t[k], g.y + r2);
            }
        }
    }

    // ---- phase 4: elementwise loss terms for this thread's 4 pixels (rows i0..i0+3, col j)
    float sPT = 0.0f, sP = 0.0f, sT = 0.0f, sBCE = 0.0f, sFOC = 0.0f, sBND = 0.0f;
    #pragma unroll
    for (int k = 0; k < 4; ++k) {
        int idx = (b * HH + (i0 + k)) * WW + j;
        float x = pred[idx];
        float t = targ[idx];

        sBND += fabsf(sqrtf(d2p[k]) - sqrtf(d2t[k]));

        float p   = 1.0f / (1.0f + expf(-x));
        float ax  = fabsf(x);
        float l1p = log1pf(expf(-ax));
        float bce_el = fmaxf(x, 0.0f) - x * t + l1p;      // BCEWithLogits
        float lsx  = fminf(x, 0.0f) - l1p;                 // log(p)
        float lsnx = -fmaxf(x, 0.0f) - l1p;                // log(1-p)
        float bce_f = -(t * lsx + (1.0f - t) * lsnx);
        float pt = p * t + (1.0f - p) * (1.0f - t);
        float om = 1.0f - pt;

        sPT  += p * t;
        sP   += p;
        sT   += t;
        sBCE += bce_el;
        sFOC += om * om * bce_f;                           // alpha=1, gamma=2
    }

    float vals[6] = { sPT, sP, sT, sBCE, sFOC, sBND };
    int lane = threadIdx.x & 63;
    int wave = threadIdx.x >> 6;
    #pragma unroll
    for (int k = 0; k < 6; ++k) {
        float v = vals[k];
        #pragma unroll
        for (int off = 32; off > 0; off >>= 1)
            v += __shfl_down(v, off, 64);
        if (lane == 0) red[wave][k] = v;
    }
    __syncthreads();
    if (threadIdx.x < 6) {
        float s = red[0][threadIdx.x] + red[1][threadIdx.x]
                + red[2][threadIdx.x] + red[3][threadIdx.x];
        atomicAdd(&ws[threadIdx.x], s);
        __threadfence();               // make this block's partials visible
    }
    __syncthreads();

    // ---- phase 5: last block to finish combines accumulators
    if (threadIdx.x == 0) {
        unsigned old = atomicAdd((unsigned*)(ws + 6), 1u);
        amLast = (old == 255u);
    }
    __syncthreads();
    if (amLast && threadIdx.x == 0) {
        float inter = atomicAdd(&ws[0], 0.0f);
        float sp    = atomicAdd(&ws[1], 0.0f);
        float st    = atomicAdd(&ws[2], 0.0f);
        float bce   = atomicAdd(&ws[3], 0.0f);
        float foc   = atomicAdd(&ws[4], 0.0f);
        float bnd   = atomicAdd(&ws[5], 0.0f);
        float invN = 1.0f / (float)NN;
        float dice = 1.0f - (2.0f * inter + 1.0f) / (sp + st + 1.0f);
        out[0] = 0.5f * dice + 0.5f * (bce * invN)
               + 0.1f * (bnd * invN) + 0.2f * (foc * invN);
    }
}

extern "C" void kernel_launch(void* const* d_in, const int* in_sizes, int n_in,
                              void* d_out, int out_size, void* d_ws, size_t ws_size,
                              hipStream_t stream) {
    const float* pred = (const float*)d_in[0];
    const float* targ = (const float*)d_in[1];
    float* ws = (float*)d_ws;

    build_masks<<<256, 64, 0, stream>>>(pred, targ, ws);
    band_fused<<<BB * 64, 256, 0, stream>>>(pred, targ, ws, (float*)d_out);
}